// Round 5
// baseline (544.472 us; speedup 1.0000x reference)
//
#include <hip/hip_runtime.h>

typedef __attribute__((ext_vector_type(2))) _Float16 half2_t;

#define NJ 7
#define HID 4

// ---- ws layout (u32 slots) ----
// [0..47]    WIHJ: 12 gates x 4 half2 (pre-scaled: g<8 by -log2e, g>=8 by 2*log2e)
// [48..71]   WHHJ: 12 gates x 2 half2 (same scaling)
// [72..95]   WIHM: 12 x 2 half2
// [96..119]  WHHM: 12 x 2 half2
// [120..127] BSUMJ rz: 8 f32   ((bih+bhh)*-log2e)
// [128..131] BIHJ_n: 4 f32     (*2log2e)
// [132..135] BHHJ_n: 4 f32     (*2log2e)
// [136..143] BSUMM rz: 8 f32
// [144..147] BIHM_n: 4 f32
// [148..151] BHHM_n: 4 f32

__device__ __forceinline__ half2_t h2(unsigned int u) {
    return __builtin_bit_cast(half2_t, u);
}
__device__ __forceinline__ float fdot2f(half2_t a, half2_t b, float c) {
#if __has_builtin(__builtin_amdgcn_fdot2)
    return __builtin_amdgcn_fdot2(a, b, c, false);
#else
    return c + (float)a.x * (float)b.x + (float)a.y * (float)b.y;
#endif
}
__device__ __forceinline__ half2_t pk(float a, float b) {
    return __builtin_bit_cast(half2_t, __builtin_amdgcn_cvt_pkrtz(a, b));
}
// 1/A,1/B,1/C,1/D with a single v_rcp_f32. A..D >= 1 and <= 2^26 -> product <= 2^104, safe.
__device__ __forceinline__ void inv4(float A, float B, float C, float D,
                                     float& ia, float& ib, float& ic, float& id) {
    float AB = A * B, CD = C * D;
    float t = __builtin_amdgcn_rcpf(AB * CD);
    float u = t * AB, v = t * CD;
    ia = v * B; ib = v * A; ic = u * D; id = u * C;
}
__device__ __forceinline__ float e2c(float a) {   // exp2(min(a,25)): keeps 1+E <= 2^26
    return __builtin_amdgcn_exp2f(fminf(a, 25.0f));
}

__global__ __launch_bounds__(256) void prep_kernel(
    const float* __restrict__ Wih_j, const float* __restrict__ Whh_j,
    const float* __restrict__ bih_j, const float* __restrict__ bhh_j,
    const float* __restrict__ Wih_m, const float* __restrict__ Whh_m,
    const float* __restrict__ bih_m, const float* __restrict__ bhh_m,
    unsigned int* __restrict__ ws)
{
    const float c1 = -1.44269504f;  // -log2(e): r,z gates
    const float c2 = 2.88539008f;   // 2*log2(e): n gates
    int t = threadIdx.x;
    if (t < 48) {                       // WIHJ
        int g = t >> 2, k = t & 3;
        float s = (g < 8) ? c1 : c2;
        ws[t] = __builtin_bit_cast(unsigned int,
                    pk(Wih_j[g*8 + 2*k] * s, Wih_j[g*8 + 2*k + 1] * s));
    } else if (t < 72) {                // WHHJ
        int i = t - 48; int g = i >> 1, k = i & 1;
        float s = (g < 8) ? c1 : c2;
        ws[t] = __builtin_bit_cast(unsigned int,
                    pk(Whh_j[g*4 + 2*k] * s, Whh_j[g*4 + 2*k + 1] * s));
    } else if (t < 96) {                // WIHM
        int i = t - 72; int g = i >> 1, k = i & 1;
        float s = (g < 8) ? c1 : c2;
        ws[t] = __builtin_bit_cast(unsigned int,
                    pk(Wih_m[g*4 + 2*k] * s, Wih_m[g*4 + 2*k + 1] * s));
    } else if (t < 120) {               // WHHM
        int i = t - 96; int g = i >> 1, k = i & 1;
        float s = (g < 8) ? c1 : c2;
        ws[t] = __builtin_bit_cast(unsigned int,
                    pk(Whh_m[g*4 + 2*k] * s, Whh_m[g*4 + 2*k + 1] * s));
    } else if (t < 128) {               // BSUMJ rz
        int g = t - 120;
        ws[t] = __float_as_uint((bih_j[g] + bhh_j[g]) * c1);
    } else if (t < 132) {               // BIHJ_n
        int i = t - 128;
        ws[t] = __float_as_uint(bih_j[8 + i] * c2);
    } else if (t < 136) {               // BHHJ_n
        int i = t - 132;
        ws[t] = __float_as_uint(bhh_j[8 + i] * c2);
    } else if (t < 144) {               // BSUMM rz
        int g = t - 136;
        ws[t] = __float_as_uint((bih_m[g] + bhh_m[g]) * c1);
    } else if (t < 148) {               // BIHM_n
        int i = t - 144;
        ws[t] = __float_as_uint(bih_m[8 + i] * c2);
    } else if (t < 152) {               // BHHM_n
        int i = t - 148;
        ws[t] = __float_as_uint(bhh_m[8 + i] * c2);
    }
}

__global__ __launch_bounds__(256, 4) void aggreg_kernel(
    const float* __restrict__ x,
    const float* __restrict__ Wj,   const float* __restrict__ bj,
    const float* __restrict__ Wm,   const float* __restrict__ bm,
    const float* __restrict__ Wact, const float* __restrict__ bact,
    const unsigned int* __restrict__ wu,
    float* __restrict__ out, int B)
{
    int row = blockIdx.x * blockDim.x + threadIdx.x;
    if (row >= B) return;

    const float* xp = x + (size_t)row * 19;
    float xr[19];
    #pragma unroll
    for (int i = 0; i < 19; ++i) xr[i] = xp[i];

    // ---- bias hoist into VGPRs (volatile defeats s_load scalarization so the
    //      per-iter accumulator inits need no SGPR->VGPR v_mov) ----
    const volatile float* bf = (const volatile float*)wu;
    float bsJ[8], biJ[4], bhJ[4], bsM[8], biM[4], bhM[4];
    #pragma unroll
    for (int g = 0; g < 8; ++g) { bsJ[g] = bf[120 + g]; bsM[g] = bf[136 + g]; }
    #pragma unroll
    for (int i = 0; i < 4; ++i) {
        biJ[i] = bf[128 + i]; bhJ[i] = bf[132 + i];
        biM[i] = bf[144 + i]; bhM[i] = bf[148 + i];
    }

    // h_j init: jcat (7,2) @ Wj.T + bj ; h_m init: obs (5) @ Wm.T + bm  (fp32, one-time)
    float hj[NJ][HID], hm[HID];
    #pragma unroll
    for (int t = 0; t < NJ; ++t)
        #pragma unroll
        for (int o = 0; o < HID; ++o)
            hj[t][o] = bj[o] + Wj[o*2+0]*xr[5+t] + Wj[o*2+1]*xr[12+t];
    #pragma unroll
    for (int o = 0; o < HID; ++o) {
        float a = bm[o];
        #pragma unroll
        for (int k = 0; k < 5; ++k) a += Wm[o*5+k]*xr[k];
        hm[o] = a;
    }

    for (int it = 0; it < 7; ++it) {
        // pack current states to half2
        half2_t hjp[NJ][2], hmp[2];
        #pragma unroll
        for (int t = 0; t < NJ; ++t) {
            hjp[t][0] = pk(hj[t][0], hj[t][1]);
            hjp[t][1] = pk(hj[t][2], hj[t][3]);
        }
        hmp[0] = pk(hm[0], hm[1]);
        hmp[1] = pk(hm[2], hm[3]);

        // ---- m-GRU: input hj[0], hidden hm ----
        float mrz[8];
        #pragma unroll
        for (int g = 0; g < 8; ++g) {
            float a = bsM[g];
            a = fdot2f(h2(wu[72 + g*2 + 0]), hjp[0][0], a);
            a = fdot2f(h2(wu[72 + g*2 + 1]), hjp[0][1], a);
            a = fdot2f(h2(wu[96 + g*2 + 0]), hmp[0], a);
            a = fdot2f(h2(wu[96 + g*2 + 1]), hmp[1], a);
            mrz[g] = a;
        }
        float mgi[4], mgh[4];
        #pragma unroll
        for (int i = 0; i < 4; ++i) {
            int gn = 8 + i;
            float gi = biM[i];
            gi = fdot2f(h2(wu[72 + gn*2 + 0]), hjp[0][0], gi);
            gi = fdot2f(h2(wu[72 + gn*2 + 1]), hjp[0][1], gi);
            float gh = bhM[i];
            gh = fdot2f(h2(wu[96 + gn*2 + 0]), hmp[0], gh);
            gh = fdot2f(h2(wu[96 + gn*2 + 1]), hmp[1], gh);
            mgi[i] = gi; mgh[i] = gh;
        }
        float hmn[HID];
        {
            float X[8];
            #pragma unroll
            for (int g = 0; g < 8; ++g) X[g] = 1.0f + e2c(mrz[g]);
            float r[4], z[4];
            inv4(X[0], X[1], X[2], X[3], r[0], r[1], r[2], r[3]);
            inv4(X[4], X[5], X[6], X[7], z[0], z[1], z[2], z[3]);
            float Xn[4];
            #pragma unroll
            for (int i = 0; i < 4; ++i) Xn[i] = 1.0f + e2c(mgi[i] + r[i]*mgh[i]);
            float tn[4];
            inv4(Xn[0], Xn[1], Xn[2], Xn[3], tn[0], tn[1], tn[2], tn[3]);
            #pragma unroll
            for (int i = 0; i < 4; ++i) {
                float n = fmaf(-2.0f, tn[i], 1.0f);
                hmn[i] = n + z[i] * (hm[i] - n);
            }
        }

        // ---- joint GRUs ----
        float hjn[NJ][HID];
        #pragma unroll
        for (int t = 0; t < NJ; ++t) {
            half2_t in0 = (t == 0) ? hmp[0] : hjp[t-1][0];
            half2_t in1 = (t == 0) ? hmp[1] : hjp[t-1][1];
            float rz[8];
            #pragma unroll
            for (int g = 0; g < 8; ++g) {
                float a = bsJ[g];
                a = fdot2f(h2(wu[g*4 + 0]), in0, a);
                a = fdot2f(h2(wu[g*4 + 1]), in1, a);
                if (t < 6) {
                    a = fdot2f(h2(wu[g*4 + 2]), hjp[t+1][0], a);
                    a = fdot2f(h2(wu[g*4 + 3]), hjp[t+1][1], a);
                }
                a = fdot2f(h2(wu[48 + g*2 + 0]), hjp[t][0], a);
                a = fdot2f(h2(wu[48 + g*2 + 1]), hjp[t][1], a);
                rz[g] = a;
            }
            float gi4[4], gh4[4];
            #pragma unroll
            for (int i = 0; i < 4; ++i) {
                int gn = 8 + i;
                float gi = biJ[i];
                gi = fdot2f(h2(wu[gn*4 + 0]), in0, gi);
                gi = fdot2f(h2(wu[gn*4 + 1]), in1, gi);
                if (t < 6) {
                    gi = fdot2f(h2(wu[gn*4 + 2]), hjp[t+1][0], gi);
                    gi = fdot2f(h2(wu[gn*4 + 3]), hjp[t+1][1], gi);
                }
                float gh = bhJ[i];
                gh = fdot2f(h2(wu[48 + gn*2 + 0]), hjp[t][0], gh);
                gh = fdot2f(h2(wu[48 + gn*2 + 1]), hjp[t][1], gh);
                gi4[i] = gi; gh4[i] = gh;
            }
            float X[8];
            #pragma unroll
            for (int g = 0; g < 8; ++g) X[g] = 1.0f + e2c(rz[g]);
            float r[4], z[4];
            inv4(X[0], X[1], X[2], X[3], r[0], r[1], r[2], r[3]);
            inv4(X[4], X[5], X[6], X[7], z[0], z[1], z[2], z[3]);
            float Xn[4];
            #pragma unroll
            for (int i = 0; i < 4; ++i) Xn[i] = 1.0f + e2c(gi4[i] + r[i]*gh4[i]);
            float tn[4];
            inv4(Xn[0], Xn[1], Xn[2], Xn[3], tn[0], tn[1], tn[2], tn[3]);
            #pragma unroll
            for (int i = 0; i < 4; ++i) {
                float n = fmaf(-2.0f, tn[i], 1.0f);
                hjn[t][i] = n + z[i] * (hj[t][i] - n);
            }
        }

        #pragma unroll
        for (int t = 0; t < NJ; ++t)
            #pragma unroll
            for (int i = 0; i < HID; ++i) hj[t][i] = hjn[t][i];
        #pragma unroll
        for (int i = 0; i < HID; ++i) hm[i] = hmn[i];
    }

    float* op = out + (size_t)row * 7;
    #pragma unroll
    for (int t = 0; t < NJ; ++t) {
        float a = bact[0];
        #pragma unroll
        for (int k = 0; k < HID; ++k) a += Wact[k] * hj[t][k];
        op[t] = a;
    }
}

extern "C" void kernel_launch(void* const* d_in, const int* in_sizes, int n_in,
                              void* d_out, int out_size, void* d_ws, size_t ws_size,
                              hipStream_t stream) {
    const float* x      = (const float*)d_in[0];
    const float* Wj     = (const float*)d_in[1];
    const float* bj     = (const float*)d_in[2];
    const float* Wm     = (const float*)d_in[3];
    const float* bm     = (const float*)d_in[4];
    const float* Wih_j  = (const float*)d_in[5];
    const float* Whh_j  = (const float*)d_in[6];
    const float* bih_j  = (const float*)d_in[7];
    const float* bhh_j  = (const float*)d_in[8];
    const float* Wih_m  = (const float*)d_in[9];
    const float* Whh_m  = (const float*)d_in[10];
    const float* bih_m  = (const float*)d_in[11];
    const float* bhh_m  = (const float*)d_in[12];
    const float* Wact   = (const float*)d_in[13];
    const float* bact   = (const float*)d_in[14];
    float* out = (float*)d_out;
    unsigned int* ws = (unsigned int*)d_ws;

    prep_kernel<<<1, 256, 0, stream>>>(Wih_j, Whh_j, bih_j, bhh_j,
                                       Wih_m, Whh_m, bih_m, bhh_m, ws);

    int B = in_sizes[0] / 19;
    const int block = 256;
    const int grid  = (B + block - 1) / block;
    aggreg_kernel<<<grid, block, 0, stream>>>(
        x, Wj, bj, Wm, bm, Wact, bact, ws, out, B);
}

// Round 6
// 508.110 us; speedup vs baseline: 1.0716x; 1.0716x over previous
//
#include <hip/hip_runtime.h>

typedef __attribute__((ext_vector_type(2))) _Float16 half2_t;

#define NJ 7
#define HID 4

// ---- ws layout (u32 slots) ----
// [0..47]    WIHJ: 12 gates x 4 half2 (pre-scaled: g<8 by -log2e, g>=8 by 2*log2e)
// [48..71]   WHHJ: 12 gates x 2 half2 (same scaling)
// [72..95]   WIHM: 12 x 2 half2
// [96..119]  WHHM: 12 x 2 half2
// [120..127] BSUMJ rz: 8 f32   ((bih+bhh)*-log2e)
// [128..131] BIHJ_n: 4 f32     (*2log2e)
// [132..135] BHHJ_n: 4 f32     (*2log2e)
// [136..143] BSUMM rz: 8 f32
// [144..147] BIHM_n: 4 f32
// [148..151] BHHM_n: 4 f32

__device__ __forceinline__ half2_t h2(unsigned int u) {
    return __builtin_bit_cast(half2_t, u);
}
__device__ __forceinline__ float fdot2f(half2_t a, half2_t b, float c) {
#if __has_builtin(__builtin_amdgcn_fdot2)
    return __builtin_amdgcn_fdot2(a, b, c, false);
#else
    return c + (float)a.x * (float)b.x + (float)a.y * (float)b.y;
#endif
}
__device__ __forceinline__ half2_t pk(float a, float b) {
    return __builtin_bit_cast(half2_t, __builtin_amdgcn_cvt_pkrtz(a, b));
}

__global__ __launch_bounds__(256) void prep_kernel(
    const float* __restrict__ Wih_j, const float* __restrict__ Whh_j,
    const float* __restrict__ bih_j, const float* __restrict__ bhh_j,
    const float* __restrict__ Wih_m, const float* __restrict__ Whh_m,
    const float* __restrict__ bih_m, const float* __restrict__ bhh_m,
    unsigned int* __restrict__ ws)
{
    const float c1 = -1.44269504f;  // -log2(e): r,z gates
    const float c2 = 2.88539008f;   // 2*log2(e): n gates
    int t = threadIdx.x;
    if (t < 48) {                       // WIHJ
        int g = t >> 2, k = t & 3;
        float s = (g < 8) ? c1 : c2;
        ws[t] = __builtin_bit_cast(unsigned int,
                    pk(Wih_j[g*8 + 2*k] * s, Wih_j[g*8 + 2*k + 1] * s));
    } else if (t < 72) {                // WHHJ
        int i = t - 48; int g = i >> 1, k = i & 1;
        float s = (g < 8) ? c1 : c2;
        ws[t] = __builtin_bit_cast(unsigned int,
                    pk(Whh_j[g*4 + 2*k] * s, Whh_j[g*4 + 2*k + 1] * s));
    } else if (t < 96) {                // WIHM
        int i = t - 72; int g = i >> 1, k = i & 1;
        float s = (g < 8) ? c1 : c2;
        ws[t] = __builtin_bit_cast(unsigned int,
                    pk(Wih_m[g*4 + 2*k] * s, Wih_m[g*4 + 2*k + 1] * s));
    } else if (t < 120) {               // WHHM
        int i = t - 96; int g = i >> 1, k = i & 1;
        float s = (g < 8) ? c1 : c2;
        ws[t] = __builtin_bit_cast(unsigned int,
                    pk(Whh_m[g*4 + 2*k] * s, Whh_m[g*4 + 2*k + 1] * s));
    } else if (t < 128) {               // BSUMJ rz
        int g = t - 120;
        ws[t] = __float_as_uint((bih_j[g] + bhh_j[g]) * c1);
    } else if (t < 132) {               // BIHJ_n
        int i = t - 128;
        ws[t] = __float_as_uint(bih_j[8 + i] * c2);
    } else if (t < 136) {               // BHHJ_n
        int i = t - 132;
        ws[t] = __float_as_uint(bhh_j[8 + i] * c2);
    } else if (t < 144) {               // BSUMM rz
        int g = t - 136;
        ws[t] = __float_as_uint((bih_m[g] + bhh_m[g]) * c1);
    } else if (t < 148) {               // BIHM_n
        int i = t - 144;
        ws[t] = __float_as_uint(bih_m[8 + i] * c2);
    } else if (t < 152) {               // BHHM_n
        int i = t - 148;
        ws[t] = __float_as_uint(bhh_m[8 + i] * c2);
    }
}

__global__ __launch_bounds__(256, 4) void aggreg_kernel(
    const float* __restrict__ x,
    const float* __restrict__ Wj,   const float* __restrict__ bj,
    const float* __restrict__ Wm,   const float* __restrict__ bm,
    const float* __restrict__ Wact, const float* __restrict__ bact,
    const unsigned int* __restrict__ wu,
    float* __restrict__ out, int B)
{
    int row = blockIdx.x * blockDim.x + threadIdx.x;
    if (row >= B) return;

    // ---- vectorized x load (19 f32 = 4x float4 + 3) ----
    const float* xp = x + (size_t)row * 19;
    float4 v0 = *(const float4*)(xp + 0);
    float4 v1 = *(const float4*)(xp + 4);
    float4 v2 = *(const float4*)(xp + 8);
    float4 v3 = *(const float4*)(xp + 12);
    float xr[19] = { v0.x, v0.y, v0.z, v0.w,  v1.x, v1.y, v1.z, v1.w,
                     v2.x, v2.y, v2.z, v2.w,  v3.x, v3.y, v3.z, v3.w,
                     xp[16], xp[17], xp[18] };

    // h_j init: jcat (7,2) @ Wj.T + bj ; h_m init: obs (5) @ Wm.T + bm
    float hj[NJ][HID], hm[HID];
    #pragma unroll
    for (int t = 0; t < NJ; ++t)
        #pragma unroll
        for (int o = 0; o < HID; ++o)
            hj[t][o] = bj[o] + Wj[o*2+0]*xr[5+t] + Wj[o*2+1]*xr[12+t];
    #pragma unroll
    for (int o = 0; o < HID; ++o) {
        float a = bm[o];
        #pragma unroll
        for (int k = 0; k < 5; ++k) a += Wm[o*5+k]*xr[k];
        hm[o] = a;
    }

    // ---- bias hoist: load once, pin into VGPRs (kills per-iter v_mov inits
    //      from the SGPR constant-bus conflict with the weight operand) ----
    float bsJ[8], biJ[4], bhJ[4], bsM[8], biM[4], bhM[4];
    #pragma unroll
    for (int g = 0; g < 8; ++g) {
        bsJ[g] = __uint_as_float(wu[120 + g]);  asm volatile("" : "+v"(bsJ[g]));
        bsM[g] = __uint_as_float(wu[136 + g]);  asm volatile("" : "+v"(bsM[g]));
    }
    #pragma unroll
    for (int i = 0; i < 4; ++i) {
        biJ[i] = __uint_as_float(wu[128 + i]);  asm volatile("" : "+v"(biJ[i]));
        bhJ[i] = __uint_as_float(wu[132 + i]);  asm volatile("" : "+v"(bhJ[i]));
        biM[i] = __uint_as_float(wu[144 + i]);  asm volatile("" : "+v"(biM[i]));
        bhM[i] = __uint_as_float(wu[148 + i]);  asm volatile("" : "+v"(bhM[i]));
    }

    for (int it = 0; it < 7; ++it) {
        // snapshot of OLD states, packed to half2 (all cross-unit reads use these)
        half2_t hjp[NJ][2], hmp[2];
        #pragma unroll
        for (int t = 0; t < NJ; ++t) {
            hjp[t][0] = pk(hj[t][0], hj[t][1]);
            hjp[t][1] = pk(hj[t][2], hj[t][3]);
        }
        hmp[0] = pk(hm[0], hm[1]);
        hmp[1] = pk(hm[2], hm[3]);

        // ---- m-GRU: input hj[0] (old pack), hidden hm; in-place update ----
        {
            float mrz[8];
            #pragma unroll
            for (int g = 0; g < 8; ++g) {
                float a = bsM[g];
                a = fdot2f(h2(wu[72 + g*2 + 0]), hjp[0][0], a);
                a = fdot2f(h2(wu[72 + g*2 + 1]), hjp[0][1], a);
                a = fdot2f(h2(wu[96 + g*2 + 0]), hmp[0], a);
                a = fdot2f(h2(wu[96 + g*2 + 1]), hmp[1], a);
                mrz[g] = a;
            }
            #pragma unroll
            for (int i = 0; i < 4; ++i) {
                int gn = 8 + i;
                float gi = biM[i];
                gi = fdot2f(h2(wu[72 + gn*2 + 0]), hjp[0][0], gi);
                gi = fdot2f(h2(wu[72 + gn*2 + 1]), hjp[0][1], gi);
                float gh = bhM[i];
                gh = fdot2f(h2(wu[96 + gn*2 + 0]), hmp[0], gh);
                gh = fdot2f(h2(wu[96 + gn*2 + 1]), hmp[1], gh);
                float r = __builtin_amdgcn_rcpf(1.0f + __builtin_amdgcn_exp2f(mrz[i]));
                float z = __builtin_amdgcn_rcpf(1.0f + __builtin_amdgcn_exp2f(mrz[4+i]));
                float v = gi + r * gh;
                float n = 1.0f - 2.0f * __builtin_amdgcn_rcpf(__builtin_amdgcn_exp2f(v) + 1.0f);
                hm[i] = n + z * (hm[i] - n);   // in-place: joints read hmp (old)
            }
        }

        // ---- joint GRUs: all inputs from old packs; in-place update ----
        #pragma unroll
        for (int t = 0; t < NJ; ++t) {
            half2_t in0 = (t == 0) ? hmp[0] : hjp[t-1][0];
            half2_t in1 = (t == 0) ? hmp[1] : hjp[t-1][1];
            float rz[8];
            #pragma unroll
            for (int g = 0; g < 8; ++g) {
                float a = bsJ[g];
                a = fdot2f(h2(wu[g*4 + 0]), in0, a);
                a = fdot2f(h2(wu[g*4 + 1]), in1, a);
                if (t < 6) {
                    a = fdot2f(h2(wu[g*4 + 2]), hjp[t+1][0], a);
                    a = fdot2f(h2(wu[g*4 + 3]), hjp[t+1][1], a);
                }
                a = fdot2f(h2(wu[48 + g*2 + 0]), hjp[t][0], a);
                a = fdot2f(h2(wu[48 + g*2 + 1]), hjp[t][1], a);
                rz[g] = a;
            }
            #pragma unroll
            for (int i = 0; i < 4; ++i) {
                int gn = 8 + i;
                float gi = biJ[i];
                gi = fdot2f(h2(wu[gn*4 + 0]), in0, gi);
                gi = fdot2f(h2(wu[gn*4 + 1]), in1, gi);
                if (t < 6) {
                    gi = fdot2f(h2(wu[gn*4 + 2]), hjp[t+1][0], gi);
                    gi = fdot2f(h2(wu[gn*4 + 3]), hjp[t+1][1], gi);
                }
                float gh = bhJ[i];
                gh = fdot2f(h2(wu[48 + gn*2 + 0]), hjp[t][0], gh);
                gh = fdot2f(h2(wu[48 + gn*2 + 1]), hjp[t][1], gh);
                float r = __builtin_amdgcn_rcpf(1.0f + __builtin_amdgcn_exp2f(rz[i]));
                float z = __builtin_amdgcn_rcpf(1.0f + __builtin_amdgcn_exp2f(rz[4+i]));
                float v = gi + r * gh;
                float n = 1.0f - 2.0f * __builtin_amdgcn_rcpf(__builtin_amdgcn_exp2f(v) + 1.0f);
                hj[t][i] = n + z * (hj[t][i] - n);  // in-place: peers read hjp (old)
            }
        }
    }

    float* op = out + (size_t)row * 7;
    #pragma unroll
    for (int t = 0; t < NJ; ++t) {
        float a = bact[0];
        #pragma unroll
        for (int k = 0; k < HID; ++k) a += Wact[k] * hj[t][k];
        op[t] = a;
    }
}

extern "C" void kernel_launch(void* const* d_in, const int* in_sizes, int n_in,
                              void* d_out, int out_size, void* d_ws, size_t ws_size,
                              hipStream_t stream) {
    const float* x      = (const float*)d_in[0];
    const float* Wj     = (const float*)d_in[1];
    const float* bj     = (const float*)d_in[2];
    const float* Wm     = (const float*)d_in[3];
    const float* bm     = (const float*)d_in[4];
    const float* Wih_j  = (const float*)d_in[5];
    const float* Whh_j  = (const float*)d_in[6];
    const float* bih_j  = (const float*)d_in[7];
    const float* bhh_j  = (const float*)d_in[8];
    const float* Wih_m  = (const float*)d_in[9];
    const float* Whh_m  = (const float*)d_in[10];
    const float* bih_m  = (const float*)d_in[11];
    const float* bhh_m  = (const float*)d_in[12];
    const float* Wact   = (const float*)d_in[13];
    const float* bact   = (const float*)d_in[14];
    float* out = (float*)d_out;
    unsigned int* ws = (unsigned int*)d_ws;

    prep_kernel<<<1, 256, 0, stream>>>(Wih_j, Whh_j, bih_j, bhh_j,
                                       Wih_m, Whh_m, bih_m, bhh_m, ws);

    int B = in_sizes[0] / 19;
    const int block = 256;
    const int grid  = (B + block - 1) / block;
    aggreg_kernel<<<grid, block, 0, stream>>>(
        x, Wj, bj, Wm, bm, Wact, bact, ws, out, B);
}